// Round 4
// baseline (382.181 us; speedup 1.0000x reference)
//
#include <hip/hip_runtime.h>
#include <stdint.h>

typedef __attribute__((ext_vector_type(8))) short bf16x8;   // 8 bf16 in 4 VGPRs
typedef __attribute__((ext_vector_type(4))) float f32x4;

#define M_DIM 8192
#define N_DIM 8192
#define K_DIM 2048
#define BK 32
#define NT (K_DIM / BK)   // 64 K-tiles

__device__ __forceinline__ unsigned short f2bf(float f) {
  uint32_t b = __builtin_bit_cast(uint32_t, f);
  b = (b + 0x7FFFu + ((b >> 16) & 1u)) >> 16;   // round-to-nearest-even
  return (unsigned short)b;
}

__device__ __forceinline__ unsigned short tern(float w) {
  return (fabsf(w) > 0.4f) ? ((w > 0.f) ? (unsigned short)0x3F80 : (unsigned short)0xBF80)
                           : (unsigned short)0;
}

// Fused pre-pass: x (fp32) -> bf16, W (fp32) -> ternary bf16.
__global__ void tl_convert(const float* __restrict__ x, const float* __restrict__ W,
                           unsigned short* __restrict__ xb, unsigned short* __restrict__ wb,
                           int n4) {
  int i = blockIdx.x * blockDim.x + threadIdx.x;
  int stride = gridDim.x * blockDim.x;
  for (; i < n4; i += stride) {
    float4 v = reinterpret_cast<const float4*>(x)[i];
    ushort4 o;
    o.x = f2bf(v.x); o.y = f2bf(v.y); o.z = f2bf(v.z); o.w = f2bf(v.w);
    reinterpret_cast<ushort4*>(xb)[i] = o;
    float4 w = reinterpret_cast<const float4*>(W)[i];
    ushort4 t;
    t.x = tern(w.x); t.y = tern(w.y); t.z = tern(w.z); t.w = tern(w.w);
    reinterpret_cast<ushort4*>(wb)[i] = t;
  }
}

// C[t,o] = sum_k A[t,k]*B[o,k]. A:[M,K] bf16, B:[N,K] bf16, row-major.
// 256x256 tile, BK=32, 8 waves (2M x 4N), per-wave 128x64 via 8x4 frags.
// 3-buffer LDS (96 KiB). ONE barrier + ONE counted vmcnt(4) per K-tile
// (3-buffer rotation makes mid-tile barriers unnecessary: stage target
// buf[(T+2)%3] is read by nobody until two boundaries later).
// Within a tile: stages issue first (max landing time), 12 ds_read_b128 in
// pinned groups, MFMA ramps behind counted lgkm sub-waits (DS completes
// in-order) -> waves drift out of lockstep, MFMA overlaps other waves' reads.
__global__ __launch_bounds__(512, 2)
void tl_gemm(const unsigned short* __restrict__ A, const unsigned short* __restrict__ B,
             float* __restrict__ C) {
  __shared__ unsigned short sA[3][256 * BK];   // 3 x 16 KiB
  __shared__ unsigned short sB[3][256 * BK];   // 3 x 16 KiB

  const int tid  = threadIdx.x;
  const int lane = tid & 63;
  const int w    = tid >> 6;       // wave 0..7
  const int wm   = w >> 2;         // 0..1 -> rows wm*128
  const int wn   = w & 3;          // 0..3 -> cols wn*64

  // XCD-aware bijective swizzle: nwg = 1024 = 8 * 128
  int bid = blockIdx.x;
  int swz = (bid & 7) * 128 + (bid >> 3);
  const int tm = swz >> 5;
  const int tn = swz & 31;
  const size_t brow = (size_t)tm * 256;
  const size_t bcol = (size_t)tn * 256;

  const int fr = lane & 15;        // fragment row index
  const int k8 = lane >> 4;        // k slot 0..3

  // ---- LDS read offsets (halves). swizzle uses row bits 1-2 (row stride 64B:
  // bit0 picks the 16-bank half; bits1-2 pick the 16B slot) -> 0 conflicts (R3) ----
  const int colh   = (k8 * 8) ^ (((fr >> 1) & 3) << 3);
  const int base_a = (wm * 128 + fr) * BK + colh;     // + mi*16*BK
  const int base_b = (wn * 64  + fr) * BK + colh;     // + ni*16*BK

  // ---- staging: one load = 512 thr x 16B = 128 rows x 64B (source pre-swizzled) ----
  const int src_colh = (((lane & 3) ^ ((lane >> 3) & 3)) * 8);
  const unsigned short* gA0 = A + (brow + w * 16 + (lane >> 2)) * (size_t)K_DIM + src_colh;
  const unsigned short* gB0 = B + (bcol + w * 16 + (lane >> 2)) * (size_t)K_DIM + src_colh;

#define STAGE_A(bufi, kt, j) do {                                                    \
    const unsigned short* g = gA0 + (size_t)(j) * 128 * K_DIM + (kt);                \
    unsigned short* l = (unsigned short*)&sA[bufi][((j) * 128 + w * 16) * BK];       \
    __builtin_amdgcn_global_load_lds((const __attribute__((address_space(1))) void*)g, \
        (__attribute__((address_space(3))) void*)l, 16, 0, 0);                       \
  } while (0)
#define STAGE_B(bufi, kt, j) do {                                                    \
    const unsigned short* g = gB0 + (size_t)(j) * 128 * K_DIM + (kt);                \
    unsigned short* l = (unsigned short*)&sB[bufi][((j) * 128 + w * 16) * BK];       \
    __builtin_amdgcn_global_load_lds((const __attribute__((address_space(1))) void*)g, \
        (__attribute__((address_space(3))) void*)l, 16, 0, 0);                       \
  } while (0)

  f32x4 acc[8][4];
  #pragma unroll
  for (int i = 0; i < 8; ++i)
    #pragma unroll
    for (int j = 0; j < 4; ++j)
      acc[i][j] = f32x4{0.f, 0.f, 0.f, 0.f};

  // ---- prologue: tile 0 -> buf0, tile 1 -> buf1 ----
  STAGE_A(0, 0, 0); STAGE_A(0, 0, 1); STAGE_B(0, 0, 0); STAGE_B(0, 0, 1);
  STAGE_A(1, BK, 0); STAGE_A(1, BK, 1); STAGE_B(1, BK, 0); STAGE_B(1, BK, 1);
  asm volatile("s_waitcnt vmcnt(4)" ::: "memory");   // tile 0 resident; tile 1 in flight
  __builtin_amdgcn_s_barrier();
  __builtin_amdgcn_sched_barrier(0);

#define MFMA(a_, b_, c_) c_ = __builtin_amdgcn_mfma_f32_16x16x32_bf16(a_, b_, c_, 0, 0, 0)

  int cur = 0;
  for (int T = 0; T < NT; ++T) {
    const int nxt2 = (cur == 0) ? 2 : cur - 1;             // (T+2) % 3
    const int kt2  = ((T + 2) & (NT - 1)) * BK;            // wraps to dummy (harmless)

    // ---- stage tile T+2 early (vm ops; max time to land) ----
    STAGE_A(nxt2, kt2, 0); STAGE_A(nxt2, kt2, 1);
    STAGE_B(nxt2, kt2, 0); STAGE_B(nxt2, kt2, 1);
    __builtin_amdgcn_sched_barrier(0);

    // ---- 12 ds_read_b128 in pinned groups (DS completes in order) ----
    bf16x8 av0 = *(const bf16x8*)&sA[cur][base_a + 0 * 16 * BK];
    bf16x8 av1 = *(const bf16x8*)&sA[cur][base_a + 1 * 16 * BK];
    bf16x8 bv0 = *(const bf16x8*)&sB[cur][base_b + 0 * 16 * BK];
    bf16x8 bv1 = *(const bf16x8*)&sB[cur][base_b + 1 * 16 * BK];
    bf16x8 bv2 = *(const bf16x8*)&sB[cur][base_b + 2 * 16 * BK];
    bf16x8 bv3 = *(const bf16x8*)&sB[cur][base_b + 3 * 16 * BK];
    __builtin_amdgcn_sched_barrier(0);
    bf16x8 av2 = *(const bf16x8*)&sA[cur][base_a + 2 * 16 * BK];
    bf16x8 av3 = *(const bf16x8*)&sA[cur][base_a + 3 * 16 * BK];
    __builtin_amdgcn_sched_barrier(0);
    bf16x8 av4 = *(const bf16x8*)&sA[cur][base_a + 4 * 16 * BK];
    bf16x8 av5 = *(const bf16x8*)&sA[cur][base_a + 5 * 16 * BK];
    __builtin_amdgcn_sched_barrier(0);
    bf16x8 av6 = *(const bf16x8*)&sA[cur][base_a + 6 * 16 * BK];
    bf16x8 av7 = *(const bf16x8*)&sA[cur][base_a + 7 * 16 * BK];
    __builtin_amdgcn_sched_barrier(0);

    __builtin_amdgcn_s_setprio(1);
    // group 1: av0,av1 x bv0-3 (needs first 6 reads)
    asm volatile("s_waitcnt lgkmcnt(6)" ::: "memory");
    __builtin_amdgcn_sched_barrier(0);
    MFMA(av0, bv0, acc[0][0]); MFMA(av0, bv1, acc[0][1]);
    MFMA(av0, bv2, acc[0][2]); MFMA(av0, bv3, acc[0][3]);
    MFMA(av1, bv0, acc[1][0]); MFMA(av1, bv1, acc[1][1]);
    MFMA(av1, bv2, acc[1][2]); MFMA(av1, bv3, acc[1][3]);
    // group 2: av2,av3
    asm volatile("s_waitcnt lgkmcnt(4)" ::: "memory");
    __builtin_amdgcn_sched_barrier(0);
    MFMA(av2, bv0, acc[2][0]); MFMA(av2, bv1, acc[2][1]);
    MFMA(av2, bv2, acc[2][2]); MFMA(av2, bv3, acc[2][3]);
    MFMA(av3, bv0, acc[3][0]); MFMA(av3, bv1, acc[3][1]);
    MFMA(av3, bv2, acc[3][2]); MFMA(av3, bv3, acc[3][3]);
    // group 3: av4,av5
    asm volatile("s_waitcnt lgkmcnt(2)" ::: "memory");
    __builtin_amdgcn_sched_barrier(0);
    MFMA(av4, bv0, acc[4][0]); MFMA(av4, bv1, acc[4][1]);
    MFMA(av4, bv2, acc[4][2]); MFMA(av4, bv3, acc[4][3]);
    MFMA(av5, bv0, acc[5][0]); MFMA(av5, bv1, acc[5][1]);
    MFMA(av5, bv2, acc[5][2]); MFMA(av5, bv3, acc[5][3]);
    // group 4: av6,av7
    asm volatile("s_waitcnt lgkmcnt(0)" ::: "memory");
    __builtin_amdgcn_sched_barrier(0);
    MFMA(av6, bv0, acc[6][0]); MFMA(av6, bv1, acc[6][1]);
    MFMA(av6, bv2, acc[6][2]); MFMA(av6, bv3, acc[6][3]);
    MFMA(av7, bv0, acc[7][0]); MFMA(av7, bv1, acc[7][1]);
    MFMA(av7, bv2, acc[7][2]); MFMA(av7, bv3, acc[7][3]);
    __builtin_amdgcn_s_setprio(0);

    // ---- K-tile boundary: drain T+1's 4 loads, keep T+2's in flight ----
    asm volatile("s_waitcnt vmcnt(4)" ::: "memory");
    __builtin_amdgcn_s_barrier();
    __builtin_amdgcn_sched_barrier(0);

    cur = (cur == 2) ? 0 : cur + 1;
  }
#undef MFMA

  // drain dummy stages before retiring
  asm volatile("s_waitcnt vmcnt(0)" ::: "memory");

  // ---- epilogue: C/D layout col = lane&15, row = (lane>>4)*4 + reg ----
  #pragma unroll
  for (int mi = 0; mi < 8; ++mi) {
    #pragma unroll
    for (int ni = 0; ni < 4; ++ni) {
      f32x4 v = acc[mi][ni];
      size_t r0 = brow + wm * 128 + mi * 16 + k8 * 4;
      size_t c0 = bcol + wn * 64 + ni * 16 + fr;
      #pragma unroll
      for (int r = 0; r < 4; ++r)
        C[(r0 + r) * N_DIM + c0] = v[r];
    }
  }
#undef STAGE_A
#undef STAGE_B
}

// Fallback (only if ws_size is unexpectedly small): fused ternarize + fp32 tiled GEMM.
__global__ void tl_naive(const float* __restrict__ x, const float* __restrict__ W,
                         float* __restrict__ out) {
  __shared__ float sx[16][17];
  __shared__ float sw[16][17];
  int tx = threadIdx.x, ty = threadIdx.y;
  int row = blockIdx.y * 16 + ty;
  int col = blockIdx.x * 16 + tx;
  float acc = 0.f;
  for (int kt = 0; kt < K_DIM; kt += 16) {
    sx[ty][tx] = x[(size_t)row * K_DIM + kt + tx];
    float wv = W[(size_t)(blockIdx.x * 16 + ty) * K_DIM + kt + tx];
    sw[ty][tx] = (fabsf(wv) > 0.4f) ? ((wv > 0.f) ? 1.f : -1.f) : 0.f;
    __syncthreads();
    #pragma unroll
    for (int k = 0; k < 16; ++k) acc += sx[ty][k] * sw[tx][k];
    __syncthreads();
  }
  out[(size_t)row * N_DIM + col] = acc;
}

extern "C" void kernel_launch(void* const* d_in, const int* in_sizes, int n_in,
                              void* d_out, int out_size, void* d_ws, size_t ws_size,
                              hipStream_t stream) {
  const float* x = (const float*)d_in[0];
  const float* W = (const float*)d_in[1];
  float* out = (float*)d_out;

  const size_t xb_elems = (size_t)M_DIM * K_DIM;
  const size_t wb_elems = (size_t)N_DIM * K_DIM;
  const size_t need = (xb_elems + wb_elems) * sizeof(unsigned short);   // 64 MiB

  if (ws_size >= need) {
    unsigned short* xb = (unsigned short*)d_ws;
    unsigned short* wb = xb + xb_elems;
    int n4 = (int)(xb_elems / 4);
    tl_convert<<<2048, 256, 0, stream>>>(x, W, xb, wb, n4);
    tl_gemm<<<1024, 512, 0, stream>>>(xb, wb, out);
  } else {
    dim3 g(N_DIM / 16, M_DIM / 16), b(16, 16);
    tl_naive<<<g, b, 0, stream>>>(x, W, out);
  }
}

// Round 5
// 232.943 us; speedup vs baseline: 1.6407x; 1.6407x over previous
//
#include <hip/hip_runtime.h>
#include <stdint.h>

typedef __attribute__((ext_vector_type(4))) int i32x4;

#define M_DIM 8192
#define N_DIM 8192
#define K_DIM 2048
#define BK 128           // i8 elements per K-tile (128 B per row, same byte geometry as R1)
#define NT (K_DIM / BK)  // 16 K-tiles

// ---- pre-pass: per-row i8 quantization of x, exact ternarize of W to i8 ----
// one block per row (8192 blocks, 256 thr). Each thread handles 8 elements.
__global__ __launch_bounds__(256)
void tl_quant(const float* __restrict__ x, const float* __restrict__ W,
              signed char* __restrict__ xq, signed char* __restrict__ wq,
              float* __restrict__ srow) {
  __shared__ float smax[4];
  const int row = blockIdx.x;
  const int t = threadIdx.x;

  const float* xr = x + (size_t)row * K_DIM;
  float4 v0 = reinterpret_cast<const float4*>(xr)[t * 2];
  float4 v1 = reinterpret_cast<const float4*>(xr)[t * 2 + 1];
  float m = fmaxf(fmaxf(fmaxf(fabsf(v0.x), fabsf(v0.y)), fmaxf(fabsf(v0.z), fabsf(v0.w))),
                  fmaxf(fmaxf(fabsf(v1.x), fabsf(v1.y)), fmaxf(fabsf(v1.z), fabsf(v1.w))));
  #pragma unroll
  for (int off = 1; off < 64; off <<= 1)
    m = fmaxf(m, __shfl_xor(m, off, 64));
  if ((t & 63) == 0) smax[t >> 6] = m;
  __syncthreads();
  m = fmaxf(fmaxf(smax[0], smax[1]), fmaxf(smax[2], smax[3]));
  const float rs = (m > 0.f) ? 127.0f / m : 0.f;

  union { signed char c[8]; uint2 u; } qx;
  qx.c[0] = (signed char)__float2int_rn(v0.x * rs);
  qx.c[1] = (signed char)__float2int_rn(v0.y * rs);
  qx.c[2] = (signed char)__float2int_rn(v0.z * rs);
  qx.c[3] = (signed char)__float2int_rn(v0.w * rs);
  qx.c[4] = (signed char)__float2int_rn(v1.x * rs);
  qx.c[5] = (signed char)__float2int_rn(v1.y * rs);
  qx.c[6] = (signed char)__float2int_rn(v1.z * rs);
  qx.c[7] = (signed char)__float2int_rn(v1.w * rs);
  reinterpret_cast<uint2*>(xq + (size_t)row * K_DIM)[t] = qx.u;

  const float* wr = W + (size_t)row * K_DIM;
  float4 w0 = reinterpret_cast<const float4*>(wr)[t * 2];
  float4 w1 = reinterpret_cast<const float4*>(wr)[t * 2 + 1];
  union { signed char c[8]; uint2 u; } qw;
  qw.c[0] = (fabsf(w0.x) > 0.4f) ? ((w0.x > 0.f) ? 1 : -1) : 0;
  qw.c[1] = (fabsf(w0.y) > 0.4f) ? ((w0.y > 0.f) ? 1 : -1) : 0;
  qw.c[2] = (fabsf(w0.z) > 0.4f) ? ((w0.z > 0.f) ? 1 : -1) : 0;
  qw.c[3] = (fabsf(w0.w) > 0.4f) ? ((w0.w > 0.f) ? 1 : -1) : 0;
  qw.c[4] = (fabsf(w1.x) > 0.4f) ? ((w1.x > 0.f) ? 1 : -1) : 0;
  qw.c[5] = (fabsf(w1.y) > 0.4f) ? ((w1.y > 0.f) ? 1 : -1) : 0;
  qw.c[6] = (fabsf(w1.z) > 0.4f) ? ((w1.z > 0.f) ? 1 : -1) : 0;
  qw.c[7] = (fabsf(w1.w) > 0.4f) ? ((w1.w > 0.f) ? 1 : -1) : 0;
  reinterpret_cast<uint2*>(wq + (size_t)row * K_DIM)[t] = qw.u;

  if (t == 0) srow[row] = (m > 0.f) ? m / 127.0f : 0.f;
}

// ---- i8 GEMM: C[t,o] = srow[t] * sum_k xq[t,k]*wq[o,k] ----
// Exact clone of the verified R1 structure (128x128 tile, 4 waves 2x2,
// 2 barriers/tile, byte XOR swizzle (row&7)<<4 both-sides, 0 conflicts),
// with BK=128 i8 elements: identical per-tile byte geometry and instruction
// mix as R1's BK=64 bf16 tile, but only 16 K-tiles instead of 32.
__global__ __launch_bounds__(256, 3)
void tl_gemm(const signed char* __restrict__ A, const signed char* __restrict__ B,
             const float* __restrict__ srow, float* __restrict__ C) {
  __shared__ signed char sA[128 * 128];   // 16 KiB
  __shared__ signed char sB[128 * 128];   // 16 KiB

  const int tid  = threadIdx.x;
  const int lane = tid & 63;
  const int w    = tid >> 6;       // wave 0..3
  const int wr   = w >> 1;         // wave row (0..1)
  const int wc   = w & 1;          // wave col (0..1)

  // XCD-aware bijective swizzle: nwg = 4096 = 8 * 512
  int bid = blockIdx.x;
  int swz = (bid & 7) * (4096 / 8) + (bid >> 3);
  const int tm = swz >> 6;
  const int tn = swz & 63;
  const size_t brow = (size_t)tm * 128;
  const size_t bcol = (size_t)tn * 128;

  // staging: per issue a wave covers 8 rows x 128 B (64 lanes x 16 B)
  const int srow0  = w * 32 + (lane >> 3);
  const int scolb0 = (lane & 7) * 16;          // byte col base

  i32x4 acc[4][4];
  #pragma unroll
  for (int i = 0; i < 4; ++i)
    #pragma unroll
    for (int j = 0; j < 4; ++j)
      acc[i][j] = i32x4{0, 0, 0, 0};

  const int fr = lane & 15;        // fragment row
  const int k8 = lane >> 4;        // k-group 0..3

  for (int kt = 0; kt < K_DIM; kt += BK) {
    // ---- stage A,B tiles (linear LDS dest, swizzled global source) ----
    #pragma unroll
    for (int j = 0; j < 4; ++j) {
      int row  = srow0 + j * 8;
      int colb = scolb0 ^ ((row & 7) << 4);
      const signed char* ga = A + (brow + row) * (size_t)K_DIM + kt + colb;
      const signed char* gb = B + (bcol + row) * (size_t)K_DIM + kt + colb;
      signed char* la = &sA[(w * 32 + j * 8) * 128];   // wave-uniform base
      signed char* lb = &sB[(w * 32 + j * 8) * 128];
      __builtin_amdgcn_global_load_lds((const __attribute__((address_space(1))) void*)ga,
                                       (__attribute__((address_space(3))) void*)la, 16, 0, 0);
      __builtin_amdgcn_global_load_lds((const __attribute__((address_space(1))) void*)gb,
                                       (__attribute__((address_space(3))) void*)lb, 16, 0, 0);
    }
    __syncthreads();   // drains vmcnt before any wave reads LDS

    // ---- compute: 2 k-halves (64 elems each) x 16 MFMA ----
    #pragma unroll
    for (int kk = 0; kk < 2; ++kk) {
      i32x4 av[4], bv[4];
      #pragma unroll
      for (int mi = 0; mi < 4; ++mi) {
        int row  = wr * 64 + mi * 16 + fr;
        int colb = (kk * 64 + k8 * 16) ^ ((row & 7) << 4);
        av[mi] = *(const i32x4*)&sA[row * 128 + colb];
      }
      #pragma unroll
      for (int ni = 0; ni < 4; ++ni) {
        int row  = wc * 64 + ni * 16 + fr;
        int colb = (kk * 64 + k8 * 16) ^ ((row & 7) << 4);
        bv[ni] = *(const i32x4*)&sB[row * 128 + colb];
      }
      #pragma unroll
      for (int mi = 0; mi < 4; ++mi)
        #pragma unroll
        for (int ni = 0; ni < 4; ++ni)
          acc[mi][ni] = __builtin_amdgcn_mfma_i32_16x16x64_i8(av[mi], bv[ni], acc[mi][ni], 0, 0, 0);
    }
    __syncthreads();
  }

  // ---- epilogue: C/D layout col = lane&15, row = (lane>>4)*4 + reg; scale by srow ----
  #pragma unroll
  for (int mi = 0; mi < 4; ++mi) {
    size_t r0 = brow + wr * 64 + mi * 16 + k8 * 4;
    float sc0 = srow[r0 + 0], sc1 = srow[r0 + 1], sc2 = srow[r0 + 2], sc3 = srow[r0 + 3];
    #pragma unroll
    for (int ni = 0; ni < 4; ++ni) {
      i32x4 v = acc[mi][ni];
      size_t c0 = bcol + wc * 64 + ni * 16 + fr;
      C[(r0 + 0) * N_DIM + c0] = sc0 * (float)v[0];
      C[(r0 + 1) * N_DIM + c0] = sc1 * (float)v[1];
      C[(r0 + 2) * N_DIM + c0] = sc2 * (float)v[2];
      C[(r0 + 3) * N_DIM + c0] = sc3 * (float)v[3];
    }
  }
}

// Fallback (only if ws_size is unexpectedly small): fused ternarize + fp32 tiled GEMM.
__global__ void tl_naive(const float* __restrict__ x, const float* __restrict__ W,
                         float* __restrict__ out) {
  __shared__ float sx[16][17];
  __shared__ float sw[16][17];
  int tx = threadIdx.x, ty = threadIdx.y;
  int row = blockIdx.y * 16 + ty;
  int col = blockIdx.x * 16 + tx;
  float acc = 0.f;
  for (int kt = 0; kt < K_DIM; kt += 16) {
    sx[ty][tx] = x[(size_t)row * K_DIM + kt + tx];
    float wv = W[(size_t)(blockIdx.x * 16 + ty) * K_DIM + kt + tx];
    sw[ty][tx] = (fabsf(wv) > 0.4f) ? ((wv > 0.f) ? 1.f : -1.f) : 0.f;
    __syncthreads();
    #pragma unroll
    for (int k = 0; k < 16; ++k) acc += sx[ty][k] * sw[tx][k];
    __syncthreads();
  }
  out[(size_t)row * N_DIM + col] = acc;
}

extern "C" void kernel_launch(void* const* d_in, const int* in_sizes, int n_in,
                              void* d_out, int out_size, void* d_ws, size_t ws_size,
                              hipStream_t stream) {
  const float* x = (const float*)d_in[0];
  const float* W = (const float*)d_in[1];
  float* out = (float*)d_out;

  const size_t xq_bytes = (size_t)M_DIM * K_DIM;          // 16 MiB
  const size_t wq_bytes = (size_t)N_DIM * K_DIM;          // 16 MiB
  const size_t need = xq_bytes + wq_bytes + M_DIM * sizeof(float);

  if (ws_size >= need) {
    signed char* xq = (signed char*)d_ws;
    signed char* wq = xq + xq_bytes;
    float* srow = (float*)(wq + wq_bytes);
    tl_quant<<<M_DIM, 256, 0, stream>>>(x, W, xq, wq, srow);
    tl_gemm<<<4096, 256, 0, stream>>>(xq, wq, srow, out);
  } else {
    dim3 g(N_DIM / 16, M_DIM / 16), b(16, 16);
    tl_naive<<<g, b, 0, stream>>>(x, W, out);
  }
}